// Round 3
// baseline (6425.655 us; speedup 1.0000x reference)
//
#include <hip/hip_runtime.h>
#include <hip/hip_bf16.h>

typedef __attribute__((ext_vector_type(8))) short short8;
typedef __attribute__((ext_vector_type(4))) float f32x4;
typedef __attribute__((ext_vector_type(2))) unsigned long long u64x2;

#define MFMA16(a, b, c) __builtin_amdgcn_mfma_f32_16x16x32_bf16((a), (b), (c), 0, 0, 0)

// sizes
#define B_ 64
#define T_ 512

// ws layout (bytes)
#define ORG_OFF   0u          // org[0..7]=claim per xcd, [8]=spare cnt, [9]=done cnt
#define FLAGS_OFF 1024u       // 8 groups * 64B (8 member flags each)
#define HBUF_OFF  4096u       // 2 * 64 * 512 * 2B = 131072
#define CAT_OFF   135168u     // 512*64*1024*2 = 67108864
#define W0F_OFF   67244032u   // 1048576
#define W1F_OFF   68292608u   // 524288
#define WAF_OFF   68816896u   // 1048576
#define WBT_OFF   69865472u   // 2097152
#define EMBF_OFF  71962624u   // 1048576
// end: 73011200

__device__ __forceinline__ short f2bf(float f) {
  unsigned u = __float_as_uint(f);
  unsigned r = (u + 0x7fffu + ((u >> 16) & 1u)) >> 16;
  return (short)r;
}

// agent-scope coherent 16B load (LLC path, for non-XCD-local groups)
__device__ __forceinline__ short8 ld8(const short* p) {
  union { u64x2 q; short8 s; } u;
  u.q.x = __hip_atomic_load((const unsigned long long*)p, __ATOMIC_RELAXED, __HIP_MEMORY_SCOPE_AGENT);
  u.q.y = __hip_atomic_load(((const unsigned long long*)p) + 1, __ATOMIC_RELAXED, __HIP_MEMORY_SCOPE_AGENT);
  return u.s;
}

// bf16 store: fast = plain (write-through to XCD L2); slow = bypass to LLC
__device__ __forceinline__ void st_bf(short* p, float v, int fast) {
  unsigned short b = (unsigned short)f2bf(v);
  if (fast) {
    *p = (short)b;
  } else {
    unsigned vv = b;
    asm volatile("global_store_short %0, %1, off sc0 sc1" :: "v"(p), "v"(vv) : "memory");
  }
}

// ---------------------------------------------------------------------------
// Weight packing: fp32 -> bf16 MFMA B-fragment order for W0 / W1 / Wout[:, :512],
// transposed Wout[:, 512:] for logits GEMM, plus bf16 copy of emb.
// Fragment blob for (K,N): idx = ((cb*(K/32) + s)*64 + l)*8 + j
//   holds W[s*32 + (l>>4)*8 + j][cb*16 + (l&15)]
// ---------------------------------------------------------------------------
__global__ void pack_weights(const float* __restrict__ W0, const float* __restrict__ W1,
                             const float* __restrict__ Wout, const float* __restrict__ emb,
                             short* __restrict__ W0f, short* __restrict__ W1f,
                             short* __restrict__ Waf, short* __restrict__ WbT,
                             short* __restrict__ embf) {
  const int total = 524288 + 262144 + 524288 + 1048576 + 524288;
  for (int i = blockIdx.x * blockDim.x + threadIdx.x; i < total; i += gridDim.x * blockDim.x) {
    if (i < 524288) {                       // W0f: K=1024, N=512
      int j = i & 7, l = (i >> 3) & 63, rest = i >> 9;
      int s = rest & 31, cb = rest >> 5;
      int k = s * 32 + ((l >> 4) << 3) + j, n = (cb << 4) + (l & 15);
      W0f[i] = f2bf(W0[k * 512 + n]);
    } else if (i < 786432) {                // W1f: K=512, N=512
      int ii = i - 524288;
      int j = ii & 7, l = (ii >> 3) & 63, rest = ii >> 9;
      int s = rest & 15, cb = rest >> 4;
      int k = s * 32 + ((l >> 4) << 3) + j, n = (cb << 4) + (l & 15);
      W1f[ii] = f2bf(W1[k * 512 + n]);
    } else if (i < 1310720) {               // Waf: Wout[:, :512], K=1024
      int ii = i - 786432;
      int j = ii & 7, l = (ii >> 3) & 63, rest = ii >> 9;
      int s = rest & 31, cb = rest >> 5;
      int k = s * 32 + ((l >> 4) << 3) + j, n = (cb << 4) + (l & 15);
      Waf[ii] = f2bf(Wout[k * 1536 + n]);
    } else if (i < 2359296) {               // WbT[v][k] = Wout[k][512+v]
      int ii = i - 1310720;
      int v = ii >> 10, k = ii & 1023;
      WbT[ii] = f2bf(Wout[k * 1536 + 512 + v]);
    } else {                                // embf = bf16(emb)
      int ii = i - 2359296;
      embf[ii] = f2bf(emb[ii]);
    }
  }
}

// ---------------------------------------------------------------------------
// Barrier helpers. Flags are agent-scope atomics (LLC, proven coherent).
// Data ordering: __syncthreads drains all waves' store acks (vmcnt 0 before
// s_barrier) -> relaxed flag store issued after is ordered behind data.
// ---------------------------------------------------------------------------
__device__ __forceinline__ void wait_tag(unsigned* gf, unsigned tag, int inv) {
  if (threadIdx.x < 8) {
    int spins = 0;
    while (__hip_atomic_load(&gf[threadIdx.x], __ATOMIC_RELAXED, __HIP_MEMORY_SCOPE_AGENT) < tag) {
      if (++spins > (1 << 22)) break;      // stopgap: degrade, don't hang
    }
  }
  __syncthreads();
  if (inv) asm volatile("buffer_inv" ::: "memory");  // L1 invalidate (fast path, reused lines)
}

__device__ __forceinline__ void signal_tag(unsigned* gf, int mb, unsigned tag) {
  __syncthreads();                         // drains all waves' data-store acks
  if (threadIdx.x == 0) {
    asm volatile("" ::: "memory");
    __hip_atomic_store(&gf[mb], tag, __ATOMIC_RELAXED, __HIP_MEMORY_SCOPE_AGENT);
  }
}

// ---------------------------------------------------------------------------
// Persistent recurrence kernel. 64 blocks x 256 threads.
// Blocks self-organize by XCD: 8 groups (one per XCD when dispatch permits) x
// 8 members. Group g owns batch rows [8g, 8g+8); member mb owns cols
// [64mb, 64mb+64) (4 waves x 16 cols, full K per wave, no LDS reduce).
// XCD-local groups exchange h via the shared per-XCD L2 (plain stores are
// write-through L1; buffer_inv keeps L1 honest); non-local groups fall back
// to agent-scope (LLC) ops — correct under any dispatch.
// ---------------------------------------------------------------------------
__global__ __launch_bounds__(256, 1) void rnn_recur(
    const int* __restrict__ x,
    const float* __restrict__ b0, const float* __restrict__ b1, const float* __restrict__ bout,
    const short* __restrict__ W0f, const short* __restrict__ W1f, const short* __restrict__ Waf,
    const short* __restrict__ embf,
    short* __restrict__ cat, short* __restrict__ hbuf,
    unsigned* __restrict__ org, unsigned* __restrict__ flagsbase) {
  const int tid = threadIdx.x;
  const int l = tid & 63, w = tid >> 6;
  __shared__ int s_g, s_m, s_fast;
  __shared__ int x_lds[8][512];

  // ---- self-organization by XCD
  if (tid == 0) {
    unsigned xcc = __builtin_amdgcn_s_getreg(20 | (31 << 11)) & 7u;  // HW_REG_XCC_ID
    int slot = (int)__hip_atomic_fetch_add(&org[xcc], 1u, __ATOMIC_RELAXED, __HIP_MEMORY_SCOPE_AGENT);
    int sp = -1;
    if (slot >= 8)
      sp = (int)__hip_atomic_fetch_add(&org[8], 1u, __ATOMIC_RELAXED, __HIP_MEMORY_SCOPE_AGENT);
    __hip_atomic_fetch_add(&org[9], 1u, __ATOMIC_RELEASE, __HIP_MEMORY_SCOPE_AGENT);
    int spins = 0;
    while (__hip_atomic_load(&org[9], __ATOMIC_ACQUIRE, __HIP_MEMORY_SCOPE_AGENT) < 64u) {
      if (++spins > (1 << 22)) break;
    }
    unsigned c[8];
    for (int i = 0; i < 8; ++i)
      c[i] = __hip_atomic_load(&org[i], __ATOMIC_RELAXED, __HIP_MEMORY_SCOPE_AGENT);
    int g, mb;
    if (sp < 0) { g = (int)xcc; mb = slot; }
    else {                                  // spare: fill j-th deficit slot
      int want = sp, acc = 0; g = 0; mb = 0;
      for (int xx = 0; xx < 8; ++xx) {
        int d = (c[xx] < 8u) ? (8 - (int)c[xx]) : 0;
        if (want < acc + d) { g = xx; mb = (int)c[xx] + (want - acc); break; }
        acc += d;
      }
    }
    s_g = g; s_m = mb; s_fast = (c[g] >= 8u) ? 1 : 0;
  }
  __syncthreads();
  const int g = s_g, mb = s_m, fast = s_fast;

  // ---- preload this group's token ids into LDS
  for (int i = tid; i < 8 * 512; i += 256)
    x_lds[i >> 9][i & 511] = x[(g * 8 + (i >> 9)) * T_ + (i & 511)];

  // ---- weight fragments in registers (wave w owns col-block cb = mb*4+w)
  const int cb = mb * 4 + w;
  short8 w0f[32], w1f[16], waf[32];
#pragma unroll
  for (int s = 0; s < 32; ++s) w0f[s] = *(const short8*)&W0f[((cb * 32 + s) * 64 + l) * 8];
#pragma unroll
  for (int s = 0; s < 16; ++s) w1f[s] = *(const short8*)&W1f[((cb * 16 + s) * 64 + l) * 8];
#pragma unroll
  for (int s = 0; s < 32; ++s) waf[s] = *(const short8*)&Waf[((cb * 32 + s) * 64 + l) * 8];

  const int col512 = cb * 16 + (l & 15);     // this lane's output column
  const int lrow = (l & 15) & 7;             // A-frag row (rows 8..15 duplicate 0..7)
  const int kofs = (l >> 4) * 8;
  const float b0v = b0[col512], b1v = b1[col512], bOv = bout[col512];
  unsigned* gf = flagsbase + g * 16;
  __syncthreads();

  for (int t = 0; t < T_; ++t) {
    // ===== phase 1: h0 = relu([e_t ; h] @ W0 + b0) =====
    f32x4 accA = {0.f, 0.f, 0.f, 0.f}, accB = {0.f, 0.f, 0.f, 0.f};
    {
      // e-part first: independent of peers — overlaps flag propagation
      int idx = x_lds[lrow][t];
      const short* ep = embf + idx * 512 + kofs;
#pragma unroll
      for (int s = 0; s < 16; s += 2) {
        short8 a0 = *(const short8*)(ep + s * 32);
        short8 a1 = *(const short8*)(ep + s * 32 + 32);
        accA = MFMA16(a0, w0f[s], accA);
        accB = MFMA16(a1, w0f[s + 1], accB);
      }
    }
    wait_tag(gf, (unsigned)(3 * t), fast);   // h_t ready (trivial at t=0)
    {
      const short* hp = hbuf + ((t & 1) << 15) + ((g * 8 + lrow) << 9) + kofs;
      if (fast) {
#pragma unroll
        for (int s = 0; s < 16; s += 2) {
          short8 a0 = *(const short8*)(hp + s * 32);
          short8 a1 = *(const short8*)(hp + s * 32 + 32);
          accA = MFMA16(a0, w0f[16 + s], accA);
          accB = MFMA16(a1, w0f[17 + s], accB);
        }
      } else {
#pragma unroll
        for (int s = 0; s < 16; s += 2) {
          short8 a0 = ld8(hp + s * 32);
          short8 a1 = ld8(hp + s * 32 + 32);
          accA = MFMA16(a0, w0f[16 + s], accA);
          accB = MFMA16(a1, w0f[17 + s], accB);
        }
      }
    }
    {
      f32x4 hv = accA + accB;
      short* cp = cat + (t * B_ + g * 8) * 1024 + col512;
#pragma unroll
      for (int j = 0; j < 4; ++j) {
        int r = (l >> 4) * 4 + j;
        if (r < 8) st_bf(cp + r * 1024, fmaxf(hv[j] + b0v, 0.f), fast);
      }
    }
    signal_tag(gf, mb, (unsigned)(3 * t + 1));

    // ===== phase 2: h1 = relu(h0 @ W1 + b1); partial = h0 @ Wout[:512, :512] =====
    wait_tag(gf, (unsigned)(3 * t + 1), 0);  // cat[t] addresses are fresh: no inv needed
    f32x4 pA = {0.f, 0.f, 0.f, 0.f}, pB = {0.f, 0.f, 0.f, 0.f};
    {
      f32x4 hA = {0.f, 0.f, 0.f, 0.f}, hB = {0.f, 0.f, 0.f, 0.f};
      const short* c0 = cat + (t * B_ + g * 8 + lrow) * 1024 + kofs;
#pragma unroll
      for (int s = 0; s < 16; s += 2) {
        short8 a0 = *(const short8*)(c0 + s * 32);
        short8 a1 = *(const short8*)(c0 + s * 32 + 32);
        hA = MFMA16(a0, w1f[s], hA);
        hB = MFMA16(a1, w1f[s + 1], hB);
        pA = MFMA16(a0, waf[s], pA);
        pB = MFMA16(a1, waf[s + 1], pB);
      }
      f32x4 hv = hA + hB;
      short* cp = cat + (t * B_ + g * 8) * 1024 + 512 + col512;
#pragma unroll
      for (int j = 0; j < 4; ++j) {
        int r = (l >> 4) * 4 + j;
        if (r < 8) st_bf(cp + r * 1024, fmaxf(hv[j] + b1v, 0.f), fast);
      }
    }
    if (t == T_ - 1) break;                  // last h1 only feeds the logits GEMM
    signal_tag(gf, mb, (unsigned)(3 * t + 2));

    // ===== phase 3: h_new = relu(partial + h1 @ Wout[512:, :512] + bout) =====
    wait_tag(gf, (unsigned)(3 * t + 2), 0);
    {
      const short* c1 = cat + (t * B_ + g * 8 + lrow) * 1024 + 512 + kofs;
#pragma unroll
      for (int s = 0; s < 16; s += 2) {
        short8 a0 = *(const short8*)(c1 + s * 32);
        short8 a1 = *(const short8*)(c1 + s * 32 + 32);
        pA = MFMA16(a0, waf[16 + s], pA);
        pB = MFMA16(a1, waf[17 + s], pB);
      }
      f32x4 hv = pA + pB;
      short* hq = hbuf + (((t + 1) & 1) << 15) + (g * 8) * 512 + col512;
#pragma unroll
      for (int j = 0; j < 4; ++j) {
        int r = (l >> 4) * 4 + j;
        if (r < 8) st_bf(hq + r * 512, fmaxf(hv[j] + bOv, 0.f), fast);
      }
    }
    signal_tag(gf, mb, (unsigned)(3 * t + 3));
  }
}

// ---------------------------------------------------------------------------
// Logits GEMM: out[b][t][v] = cat[t*64+b][:] @ WbT[v][:] + bout[512+v]
// 128x128 tiles, 4 waves of 64x64 (4x4 16x16 frags), K-step 32, LDS staged.
// ---------------------------------------------------------------------------
__global__ __launch_bounds__(256) void logits_gemm(const short* __restrict__ cat,
                                                   const short* __restrict__ WbT,
                                                   const float* __restrict__ bout,
                                                   float* __restrict__ out) {
  const int mbase = (blockIdx.x >> 3) * 128;
  const int vbase = (blockIdx.x & 7) * 128;
  __shared__ short sA[128 * 32];
  __shared__ short sB[128 * 32];
  const int tid = threadIdx.x, l = tid & 63, w = tid >> 6;
  const int wm = w & 1, wn = w >> 1;

  f32x4 acc[4][4];
#pragma unroll
  for (int i = 0; i < 4; ++i)
#pragma unroll
    for (int j = 0; j < 4; ++j) acc[i][j] = (f32x4){0.f, 0.f, 0.f, 0.f};

  for (int kb = 0; kb < 1024; kb += 32) {
    __syncthreads();
#pragma unroll
    for (int it = 0; it < 2; ++it) {
      int c = tid + 256 * it;            // 0..511
      int ml = c >> 2, ks = c & 3;
      *(short8*)&sA[ml * 32 + ks * 8] = *(const short8*)&cat[(mbase + ml) * 1024 + kb + ks * 8];
      *(short8*)&sB[ml * 32 + ks * 8] = *(const short8*)&WbT[(vbase + ml) * 1024 + kb + ks * 8];
    }
    __syncthreads();
    short8 af[4], bf[4];
#pragma unroll
    for (int fr = 0; fr < 4; ++fr)
      af[fr] = *(const short8*)&sA[(wm * 64 + fr * 16 + (l & 15)) * 32 + (l >> 4) * 8];
#pragma unroll
    for (int fc = 0; fc < 4; ++fc)
      bf[fc] = *(const short8*)&sB[(wn * 64 + fc * 16 + (l & 15)) * 32 + (l >> 4) * 8];
#pragma unroll
    for (int fr = 0; fr < 4; ++fr)
#pragma unroll
      for (int fc = 0; fc < 4; ++fc) acc[fr][fc] = MFMA16(af[fr], bf[fc], acc[fr][fc]);
  }

  float bb[4];
#pragma unroll
  for (int fc = 0; fc < 4; ++fc) bb[fc] = bout[512 + vbase + wn * 64 + fc * 16 + (l & 15)];

#pragma unroll
  for (int fr = 0; fr < 4; ++fr) {
#pragma unroll
    for (int fc = 0; fc < 4; ++fc) {
      int v = vbase + wn * 64 + fc * 16 + (l & 15);
#pragma unroll
      for (int j = 0; j < 4; ++j) {
        int mm = mbase + wm * 64 + fr * 16 + (l >> 4) * 4 + j;
        int b = mm & 63, tt = mm >> 6;
        out[((long)(b * T_ + tt)) * 1024 + v] = acc[fr][fc][j] + bb[fc];
      }
    }
  }
}

extern "C" void kernel_launch(void* const* d_in, const int* in_sizes, int n_in,
                              void* d_out, int out_size, void* d_ws, size_t ws_size,
                              hipStream_t stream) {
  const int*   x    = (const int*)d_in[0];
  const float* emb  = (const float*)d_in[1];
  const float* W0   = (const float*)d_in[2];
  const float* b0   = (const float*)d_in[3];
  const float* W1   = (const float*)d_in[4];
  const float* b1   = (const float*)d_in[5];
  const float* Wout = (const float*)d_in[6];
  const float* bout = (const float*)d_in[7];
  float* out = (float*)d_out;

  char* ws = (char*)d_ws;
  unsigned* org   = (unsigned*)(ws + ORG_OFF);
  unsigned* flags = (unsigned*)(ws + FLAGS_OFF);
  short* hbuf = (short*)(ws + HBUF_OFF);
  short* cat  = (short*)(ws + CAT_OFF);
  short* W0f  = (short*)(ws + W0F_OFF);
  short* W1f  = (short*)(ws + W1F_OFF);
  short* Waf  = (short*)(ws + WAF_OFF);
  short* WbT  = (short*)(ws + WBT_OFF);
  short* embf = (short*)(ws + EMBF_OFF);

  // zero org/flags + h0 state (h_init = 0)
  hipMemsetAsync(ws, 0, HBUF_OFF + 131072u, stream);
  pack_weights<<<1024, 256, 0, stream>>>(W0, W1, Wout, emb, W0f, W1f, Waf, WbT, embf);
  rnn_recur<<<64, 256, 0, stream>>>(x, b0, b1, bout, W0f, W1f, Waf, embf, cat, hbuf, org, flags);
  logits_gemm<<<2048, 256, 0, stream>>>(cat, WbT, bout, out);
}